// Round 7
// baseline (2226.554 us; speedup 1.0000x reference)
//
#include <hip/hip_runtime.h>

#define N_NODES 100000
#define N_EDGES 600000
#define NB 1563              // ceil(100000/64) buckets of 64 nodes (dst>>6)
#define LDS_STRIDE 136       // ushorts per row: 128 + 8 pad

typedef __attribute__((ext_vector_type(8))) short short8;
typedef __attribute__((ext_vector_type(4))) float f32x4;
typedef __attribute__((ext_vector_type(8))) unsigned short ushort8v;

__device__ __forceinline__ unsigned short f2b(float f) {   // fp32 -> bf16 RNE
    unsigned u = __builtin_bit_cast(unsigned, f);
    return (unsigned short)((u + 0x7fffu + ((u >> 16) & 1u)) >> 16);
}
__device__ __forceinline__ float b2f(unsigned short b) {
    return __builtin_bit_cast(float, (unsigned)b << 16);
}

// ---------------------------------------------------------------------------
// Histogram of edges per 64-node bucket, per relation.
__global__ void bhist_kernel(const int* __restrict__ e0, const int* __restrict__ e1,
                             const int* __restrict__ e2, int* __restrict__ bcnt) {
    int e = blockIdx.x * blockDim.x + threadIdx.x;
    if (e >= N_EDGES) return;
    int r = blockIdx.y;
    const int* ei = (r == 0) ? e0 : (r == 1 ? e1 : e2);
    atomicAdd(&bcnt[r * NB + (ei[N_EDGES + e] >> 6)], 1);
}

// ---------------------------------------------------------------------------
// Exclusive scan of bucket counts -> bstart[r][NB+1]; also seed bcursor.
__global__ __launch_bounds__(1024) void bscan_kernel(const int* __restrict__ bcnt,
                                                     int* __restrict__ bstart,
                                                     int* __restrict__ bcursor) {
    int r = blockIdx.x;
    const int* c = bcnt + r * NB;
    __shared__ int wsum[16];
    __shared__ int s_carry;
    int tid = threadIdx.x, lane = tid & 63, wid = tid >> 6;
    if (tid == 0) s_carry = 0;
    __syncthreads();
    for (int base = 0; base < NB; base += 1024) {
        int i = base + tid;
        int v = (i < NB) ? c[i] : 0;
        int incl = v;
#pragma unroll
        for (int off = 1; off < 64; off <<= 1) {
            int t = __shfl_up(incl, off);
            if (lane >= off) incl += t;
        }
        if (lane == 63) wsum[wid] = incl;
        __syncthreads();
        if (wid == 0) {
            int wv = (lane < 16) ? wsum[lane] : 0;
#pragma unroll
            for (int off = 1; off < 16; off <<= 1) {
                int t = __shfl_up(wv, off);
                if (lane >= off) wv += t;
            }
            if (lane < 16) wsum[lane] = wv;
        }
        __syncthreads();
        int carry = s_carry;
        int woff = (wid > 0) ? wsum[wid - 1] : 0;
        if (i < NB) {
            int ex = carry + woff + (incl - v);
            bstart[r * (NB + 1) + i] = ex;
            bcursor[r * NB + i] = ex;
        }
        __syncthreads();
        if (tid == 0) s_carry = carry + wsum[15];
        __syncthreads();
    }
    if (tid == 0) bstart[r * (NB + 1) + NB] = N_EDGES;
}

// ---------------------------------------------------------------------------
// Bucket fill: append (src,dst) pairs into bucket regions (append-only writes).
__global__ void bfill_kernel(const int* __restrict__ e0, const int* __restrict__ e1,
                             const int* __restrict__ e2,
                             int* __restrict__ bcursor, int2* __restrict__ pairs) {
    int e = blockIdx.x * blockDim.x + threadIdx.x;
    if (e >= N_EDGES) return;
    int r = blockIdx.y;
    const int* ei = (r == 0) ? e0 : (r == 1 ? e1 : e2);
    int src = ei[e], dst = ei[N_EDGES + e];
    int p = atomicAdd(&bcursor[r * NB + (dst >> 6)], 1);
    pairs[(size_t)r * N_EDGES + p] = make_int2(src, dst);
}

// ---------------------------------------------------------------------------
// x (fp32) -> xb (bf16), 8 elems/thread.
__global__ void xcast_kernel(const float* __restrict__ x, unsigned short* __restrict__ xb) {
    int idx = blockIdx.x * 256 + threadIdx.x;
    const float4* p = (const float4*)x + (size_t)idx * 2;
    float4 a = p[0], b = p[1];
    ushort8v o;
    o[0] = f2b(a.x); o[1] = f2b(a.y); o[2] = f2b(a.z); o[3] = f2b(a.w);
    o[4] = f2b(b.x); o[5] = f2b(b.y); o[6] = f2b(b.z); o[7] = f2b(b.w);
    *(ushort8v*)(xb + (size_t)idx * 8) = o;
}

// ---------------------------------------------------------------------------
// Pre-swizzle weights into MFMA B-fragment order (coalesced lane*16B bursts).
__global__ void wprep_kernel(const float* __restrict__ Wl, const float* __restrict__ Wr,
                             const float* __restrict__ Wl_f, const float* __restrict__ Wr_f,
                             unsigned short* __restrict__ Wfrag, unsigned short* __restrict__ Wfrag2) {
    int idx = blockIdx.x * 256 + threadIdx.x;      // 448 blocks = 114688 threads
    int j = idx & 7, lane = (idx >> 3) & 63;
    int quad = lane >> 4, l16 = lane & 15;
    if (idx < 98304) {
        int t = (idx >> 9) & 1, s = (idx >> 10) & 7, w = (idx >> 13) & 3, r = idx >> 15;
        int k = s * 32 + quad * 8 + j;
        int n = w * 32 + t * 16 + l16;
        float v = (k < 128) ? Wl[((size_t)r * 128 + k) * 128 + n]
                            : Wr[((size_t)r * 128 + (k - 128)) * 128 + n];
        Wfrag[idx] = f2b(v);
    } else {
        int i2 = idx - 98304;
        if (i2 < 16384) {
            int t = (i2 >> 9) & 1, s = (i2 >> 10) & 3, w = (i2 >> 12) & 3;
            int k = s * 32 + quad * 8 + j;
            int n = w * 32 + t * 16 + l16;
            float v = (n < 64) ? Wl_f[(size_t)k * 64 + n] : Wr_f[(size_t)k * 64 + (n - 64)];
            Wfrag2[i2] = f2b(v);
        }
    }
}

// ---------------------------------------------------------------------------
// Bucket aggregation, 128 ch: one block per 64-node bucket. Streams the
// bucket's (src,dst) pairs, accumulates xb[src] rows into LDS fp32 via
// ds_add_f32 (ch=lane split -> free 2-way banks), then writes bf16 means.
__global__ __launch_bounds__(256) void bagg128_kernel(
    const int2* __restrict__ pairs, const int* __restrict__ bstart,
    const unsigned short* __restrict__ xb, unsigned short* __restrict__ aggb) {
    __shared__ float sacc[64 * 128];
    __shared__ int scnt[64];
    int tid = threadIdx.x, wave = tid >> 6, lane = tid & 63;
    int b = blockIdx.x;
    for (int i = tid; i < 64 * 128; i += 256) sacc[i] = 0.f;
    if (tid < 64) scnt[tid] = 0;
    __syncthreads();

    int estart = bstart[b], eend = bstart[b + 1];
    int e = estart + wave;
    for (; e + 12 < eend; e += 16) {                    // 4 edges in flight/wave
        int2 p0 = pairs[e],     p1 = pairs[e + 4];
        int2 p2 = pairs[e + 8], p3 = pairs[e + 12];
        unsigned short a0 = xb[(size_t)p0.x * 128 + lane];
        unsigned short a1 = xb[(size_t)p0.x * 128 + 64 + lane];
        unsigned short b0 = xb[(size_t)p1.x * 128 + lane];
        unsigned short b1 = xb[(size_t)p1.x * 128 + 64 + lane];
        unsigned short c0 = xb[(size_t)p2.x * 128 + lane];
        unsigned short c1 = xb[(size_t)p2.x * 128 + 64 + lane];
        unsigned short d0 = xb[(size_t)p3.x * 128 + lane];
        unsigned short d1 = xb[(size_t)p3.x * 128 + 64 + lane];
        if (lane == 0) {
            atomicAdd(&scnt[p0.y & 63], 1); atomicAdd(&scnt[p1.y & 63], 1);
            atomicAdd(&scnt[p2.y & 63], 1); atomicAdd(&scnt[p3.y & 63], 1);
        }
        atomicAdd(&sacc[(p0.y & 63) * 128 + lane],      b2f(a0));
        atomicAdd(&sacc[(p0.y & 63) * 128 + 64 + lane], b2f(a1));
        atomicAdd(&sacc[(p1.y & 63) * 128 + lane],      b2f(b0));
        atomicAdd(&sacc[(p1.y & 63) * 128 + 64 + lane], b2f(b1));
        atomicAdd(&sacc[(p2.y & 63) * 128 + lane],      b2f(c0));
        atomicAdd(&sacc[(p2.y & 63) * 128 + 64 + lane], b2f(c1));
        atomicAdd(&sacc[(p3.y & 63) * 128 + lane],      b2f(d0));
        atomicAdd(&sacc[(p3.y & 63) * 128 + 64 + lane], b2f(d1));
    }
    for (; e < eend; e += 4) {                          // tail
        int2 p0 = pairs[e];
        unsigned short a0 = xb[(size_t)p0.x * 128 + lane];
        unsigned short a1 = xb[(size_t)p0.x * 128 + 64 + lane];
        if (lane == 0) atomicAdd(&scnt[p0.y & 63], 1);
        atomicAdd(&sacc[(p0.y & 63) * 128 + lane],      b2f(a0));
        atomicAdd(&sacc[(p0.y & 63) * 128 + 64 + lane], b2f(a1));
    }
    __syncthreads();

    for (int i = tid; i < 64 * 16; i += 256) {          // bf16 means, coalesced
        int row = i >> 4, c = i & 15;
        float inv = 1.0f / fmaxf((float)scnt[row], 1.0f);
        ushort8v o;
#pragma unroll
        for (int k = 0; k < 8; k++) o[k] = f2b(sacc[row * 128 + c * 8 + k] * inv);
        *(ushort8v*)(aggb + ((size_t)b * 64 + row) * 128 + c * 8) = o;
    }
}

// ---------------------------------------------------------------------------
// Bucket aggregation, 64 ch (final layer): mean of hWlb[src] rows, += into out.
__global__ __launch_bounds__(256) void bagg64_kernel(
    const int2* __restrict__ pairs, const int* __restrict__ bstart,
    const unsigned short* __restrict__ hWlb, float* __restrict__ out) {
    __shared__ float sacc[64 * 64];
    __shared__ int scnt[64];
    int tid = threadIdx.x, wave = tid >> 6, lane = tid & 63;
    int b = blockIdx.x;
    for (int i = tid; i < 64 * 64; i += 256) sacc[i] = 0.f;
    if (tid < 64) scnt[tid] = 0;
    __syncthreads();

    int estart = bstart[b], eend = bstart[b + 1];
    int e = estart + wave;
    for (; e + 12 < eend; e += 16) {
        int2 p0 = pairs[e],     p1 = pairs[e + 4];
        int2 p2 = pairs[e + 8], p3 = pairs[e + 12];
        unsigned short v0 = hWlb[(size_t)p0.x * 64 + lane];
        unsigned short v1 = hWlb[(size_t)p1.x * 64 + lane];
        unsigned short v2 = hWlb[(size_t)p2.x * 64 + lane];
        unsigned short v3 = hWlb[(size_t)p3.x * 64 + lane];
        if (lane == 0) {
            atomicAdd(&scnt[p0.y & 63], 1); atomicAdd(&scnt[p1.y & 63], 1);
            atomicAdd(&scnt[p2.y & 63], 1); atomicAdd(&scnt[p3.y & 63], 1);
        }
        atomicAdd(&sacc[(p0.y & 63) * 64 + lane], b2f(v0));
        atomicAdd(&sacc[(p1.y & 63) * 64 + lane], b2f(v1));
        atomicAdd(&sacc[(p2.y & 63) * 64 + lane], b2f(v2));
        atomicAdd(&sacc[(p3.y & 63) * 64 + lane], b2f(v3));
    }
    for (; e < eend; e += 4) {
        int2 p0 = pairs[e];
        unsigned short v0 = hWlb[(size_t)p0.x * 64 + lane];
        if (lane == 0) atomicAdd(&scnt[p0.y & 63], 1);
        atomicAdd(&sacc[(p0.y & 63) * 64 + lane], b2f(v0));
    }
    __syncthreads();

    for (int i = tid; i < 64 * 64; i += 256) {
        int row = i >> 6;
        int node = b * 64 + row;
        if (node < N_NODES) {
            float inv = 1.0f / fmaxf((float)scnt[row], 1.0f);
            out[(size_t)node * 64 + (i & 63)] += sacc[i] * inv;
        }
    }
}

// ---------------------------------------------------------------------------
// Layer-1 for one relation: hb (+)= relu([agg|x](K=256) @ W + bl) / 3  (bf16 RMW)
__global__ __launch_bounds__(256, 4) void layer1_kernel(
    const unsigned short* __restrict__ aggb, const unsigned short* __restrict__ xb,
    const unsigned short* __restrict__ Wfrag, const float* __restrict__ bl,
    unsigned short* __restrict__ hb, int first) {
    __shared__ unsigned short s_a[64 * LDS_STRIDE];
    __shared__ unsigned short s_x[64 * LDS_STRIDE];
    int tid = threadIdx.x, wave = tid >> 6, lane = tid & 63;
    int quad = lane >> 4, l16 = lane & 15;
    int rowbase = blockIdx.x * 64;

#pragma unroll
    for (int it = 0; it < 4; it++) {
        int idx = tid + it * 256;
        int row = idx >> 4, c = idx & 15;
        int grow = rowbase + row;
        short8 xv = {0, 0, 0, 0, 0, 0, 0, 0};
        if (grow < N_NODES) xv = *(const short8*)(xb + (size_t)grow * 128 + c * 8);
        *(short8*)&s_x[row * LDS_STRIDE + c * 8] = xv;
        short8 av = *(const short8*)(aggb + (size_t)(rowbase + row) * 128 + c * 8);
        *(short8*)&s_a[row * LDS_STRIDE + c * 8] = av;
    }
    __syncthreads();

    f32x4 acc[4][2];
#pragma unroll
    for (int g = 0; g < 4; g++) { acc[g][0] = (f32x4){0.f,0.f,0.f,0.f}; acc[g][1] = (f32x4){0.f,0.f,0.f,0.f}; }

    const unsigned short* W = Wfrag + wave * 8192;
#pragma unroll
    for (int s = 0; s < 8; s++) {
        short8 bf0 = *(const short8*)(W + s * 1024 + lane * 8);         // coalesced 1KB
        short8 bf1 = *(const short8*)(W + s * 1024 + 512 + lane * 8);
        const unsigned short* src = (s < 4) ? s_a : s_x;
        int ko = (s & 3) * 32 + quad * 8;
#pragma unroll
        for (int g = 0; g < 4; g++) {
            short8 af = *(const short8*)&src[(g * 16 + l16) * LDS_STRIDE + ko];
            acc[g][0] = __builtin_amdgcn_mfma_f32_16x16x32_bf16(af, bf0, acc[g][0], 0, 0, 0);
            acc[g][1] = __builtin_amdgcn_mfma_f32_16x16x32_bf16(af, bf1, acc[g][1], 0, 0, 0);
        }
    }

    float b0 = bl[wave * 32 + l16];
    float b1 = bl[wave * 32 + 16 + l16];
#pragma unroll
    for (int g = 0; g < 4; g++)
#pragma unroll
        for (int t = 0; t < 2; t++) {
            float bb = t ? b1 : b0;
            int col = wave * 32 + t * 16 + l16;
#pragma unroll
            for (int q = 0; q < 4; q++) {
                int row = rowbase + g * 16 + quad * 4 + q;
                if (row < N_NODES) {
                    float v = fmaxf(acc[g][t][q] + bb, 0.f) * (1.0f / 3.0f);
                    size_t o = (size_t)row * 128 + col;
                    if (!first) v += b2f(hb[o]);
                    hb[o] = f2b(v);
                }
            }
        }
}

// ---------------------------------------------------------------------------
// Layer-2: [hWl|hWr] = h @ Wf2 (K=128); hWl -> bf16 buffer, out = hWr + bl_f.
__global__ __launch_bounds__(256, 4) void layer2_kernel(
    const unsigned short* __restrict__ hb, const unsigned short* __restrict__ Wfrag2,
    const float* __restrict__ bl_f, unsigned short* __restrict__ hWlb,
    float* __restrict__ out) {
    __shared__ unsigned short s_h[64 * LDS_STRIDE];
    int tid = threadIdx.x, wave = tid >> 6, lane = tid & 63;
    int quad = lane >> 4, l16 = lane & 15;
    int rowbase = blockIdx.x * 64;

#pragma unroll
    for (int it = 0; it < 4; it++) {
        int idx = tid + it * 256;
        int row = idx >> 4, c = idx & 15;
        int grow = rowbase + row;
        short8 hv = {0, 0, 0, 0, 0, 0, 0, 0};
        if (grow < N_NODES) hv = *(const short8*)(hb + (size_t)grow * 128 + c * 8);
        *(short8*)&s_h[row * LDS_STRIDE + c * 8] = hv;
    }
    __syncthreads();

    f32x4 acc[4][2];
#pragma unroll
    for (int g = 0; g < 4; g++) { acc[g][0] = (f32x4){0.f,0.f,0.f,0.f}; acc[g][1] = (f32x4){0.f,0.f,0.f,0.f}; }

    const unsigned short* W = Wfrag2 + wave * 4096;
#pragma unroll
    for (int s = 0; s < 4; s++) {
        short8 bf0 = *(const short8*)(W + s * 1024 + lane * 8);
        short8 bf1 = *(const short8*)(W + s * 1024 + 512 + lane * 8);
        int ko = s * 32 + quad * 8;
#pragma unroll
        for (int g = 0; g < 4; g++) {
            short8 af = *(const short8*)&s_h[(g * 16 + l16) * LDS_STRIDE + ko];
            acc[g][0] = __builtin_amdgcn_mfma_f32_16x16x32_bf16(af, bf0, acc[g][0], 0, 0, 0);
            acc[g][1] = __builtin_amdgcn_mfma_f32_16x16x32_bf16(af, bf1, acc[g][1], 0, 0, 0);
        }
    }

#pragma unroll
    for (int g = 0; g < 4; g++)
#pragma unroll
        for (int t = 0; t < 2; t++) {
            int col = wave * 32 + t * 16 + l16;
#pragma unroll
            for (int q = 0; q < 4; q++) {
                int row = rowbase + g * 16 + quad * 4 + q;
                if (row < N_NODES) {
                    if (col < 64) hWlb[(size_t)row * 64 + col] = f2b(acc[g][t][q]);
                    else out[(size_t)row * 64 + (col - 64)] = acc[g][t][q] + bl_f[col - 64];
                }
            }
        }
}

// ---------------------------------------------------------------------------
extern "C" void kernel_launch(void* const* d_in, const int* in_sizes, int n_in,
                              void* d_out, int out_size, void* d_ws, size_t ws_size,
                              hipStream_t stream) {
    const float* x    = (const float*)d_in[0];
    const float* Wl   = (const float*)d_in[1];
    const float* bl   = (const float*)d_in[2];
    const float* Wr   = (const float*)d_in[3];
    const float* Wl_f = (const float*)d_in[4];
    const float* bl_f = (const float*)d_in[5];
    const float* Wr_f = (const float*)d_in[6];
    const int* ei0 = (const int*)d_in[7];
    const int* ei1 = (const int*)d_in[8];
    const int* ei2 = (const int*)d_in[9];
    float* out = (float*)d_out;

    // workspace layout, total ~107 MB (<=123 MB proven budget)
    char* ws = (char*)d_ws;
    int* bcnt              = (int*)(ws);                                   // 18.8 KB
    int* bcursor           = (int*)(ws + ((size_t)64  << 10));             // 18.8 KB
    int* bstart            = (int*)(ws + ((size_t)128 << 10));             // 18.8 KB
    unsigned short* Wfrag  = (unsigned short*)(ws + ((size_t)256 << 10));  // 192 KB
    unsigned short* Wfrag2 = (unsigned short*)(ws + ((size_t)512 << 10));  // 32 KB
    int2* pairs            = (int2*)(ws + ((size_t)1  << 20));             // 14.4 MB
    unsigned short* xb     = (unsigned short*)(ws + ((size_t)16 << 20));   // 25.6 MB
    unsigned short* aggb   = (unsigned short*)(ws + ((size_t)42 << 20));   // 25.6 MB
    unsigned short* hb     = (unsigned short*)(ws + ((size_t)68 << 20));   // 25.6 MB
    unsigned short* hWlb   = (unsigned short*)(ws + ((size_t)94 << 20));   // 12.8 MB

    hipMemsetAsync(bcnt, 0, 3 * NB * sizeof(int), stream);

    dim3 ge((N_EDGES + 255) / 256, 3);
    bhist_kernel<<<ge, 256, 0, stream>>>(ei0, ei1, ei2, bcnt);
    bscan_kernel<<<3, 1024, 0, stream>>>(bcnt, bstart, bcursor);
    bfill_kernel<<<ge, 256, 0, stream>>>(ei0, ei1, ei2, bcursor, pairs);
    wprep_kernel<<<448, 256, 0, stream>>>(Wl, Wr, Wl_f, Wr_f, Wfrag, Wfrag2);
    xcast_kernel<<<(N_NODES * 128 / 8) / 256, 256, 0, stream>>>(x, xb);

    const int TILE_BLOCKS = (N_NODES + 63) / 64;   // 1563
    for (int r = 0; r < 3; r++) {
        bagg128_kernel<<<NB, 256, 0, stream>>>(
            pairs + (size_t)r * N_EDGES, bstart + r * (NB + 1), xb, aggb);
        layer1_kernel<<<TILE_BLOCKS, 256, 0, stream>>>(
            aggb, xb, Wfrag + (size_t)r * 32768, bl + r * 128, hb, r == 0 ? 1 : 0);
    }

    layer2_kernel<<<TILE_BLOCKS, 256, 0, stream>>>(hb, Wfrag2, bl_f, hWlb, out);
    bagg64_kernel<<<NB, 256, 0, stream>>>(pairs, bstart, hWlb, out);
}

// Round 8
// 774.033 us; speedup vs baseline: 2.8766x; 2.8766x over previous
//
#include <hip/hip_runtime.h>

#define N_NODES 100000
#define N_EDGES 600000
#define NB 1563              // ceil(100000/64) buckets of 64 nodes (dst>>6)
#define LDS_STRIDE 136       // ushorts per row: 128 + 8 pad

typedef __attribute__((ext_vector_type(8))) short short8;
typedef __attribute__((ext_vector_type(4))) float f32x4;
typedef __attribute__((ext_vector_type(8))) unsigned short ushort8v;

__device__ __forceinline__ unsigned short f2b(float f) {   // fp32 -> bf16 RNE
    unsigned u = __builtin_bit_cast(unsigned, f);
    return (unsigned short)((u + 0x7fffu + ((u >> 16) & 1u)) >> 16);
}
__device__ __forceinline__ float b2f(unsigned short b) {
    return __builtin_bit_cast(float, (unsigned)b << 16);
}

// ---------------------------------------------------------------------------
// Histogram of edges per 64-node bucket, per relation.
__global__ void bhist_kernel(const int* __restrict__ e0, const int* __restrict__ e1,
                             const int* __restrict__ e2, int* __restrict__ bcnt) {
    int e = blockIdx.x * blockDim.x + threadIdx.x;
    if (e >= N_EDGES) return;
    int r = blockIdx.y;
    const int* ei = (r == 0) ? e0 : (r == 1 ? e1 : e2);
    atomicAdd(&bcnt[r * NB + (ei[N_EDGES + e] >> 6)], 1);
}

// ---------------------------------------------------------------------------
// Exclusive scan of bucket counts -> bstart[r][NB+1]; seed bcursor.
__global__ __launch_bounds__(1024) void bscan_kernel(const int* __restrict__ bcnt,
                                                     int* __restrict__ bstart,
                                                     int* __restrict__ bcursor) {
    int r = blockIdx.x;
    const int* c = bcnt + r * NB;
    __shared__ int wsum[16];
    __shared__ int s_carry;
    int tid = threadIdx.x, lane = tid & 63, wid = tid >> 6;
    if (tid == 0) s_carry = 0;
    __syncthreads();
    for (int base = 0; base < NB; base += 1024) {
        int i = base + tid;
        int v = (i < NB) ? c[i] : 0;
        int incl = v;
#pragma unroll
        for (int off = 1; off < 64; off <<= 1) {
            int t = __shfl_up(incl, off);
            if (lane >= off) incl += t;
        }
        if (lane == 63) wsum[wid] = incl;
        __syncthreads();
        if (wid == 0) {
            int wv = (lane < 16) ? wsum[lane] : 0;
#pragma unroll
            for (int off = 1; off < 16; off <<= 1) {
                int t = __shfl_up(wv, off);
                if (lane >= off) wv += t;
            }
            if (lane < 16) wsum[lane] = wv;
        }
        __syncthreads();
        int carry = s_carry;
        int woff = (wid > 0) ? wsum[wid - 1] : 0;
        if (i < NB) {
            int ex = carry + woff + (incl - v);
            bstart[r * (NB + 1) + i] = ex;
            bcursor[r * NB + i] = ex;
        }
        __syncthreads();
        if (tid == 0) s_carry = carry + wsum[15];
        __syncthreads();
    }
    if (tid == 0) bstart[r * (NB + 1) + NB] = N_EDGES;
}

// ---------------------------------------------------------------------------
// Bucket fill: append packed (src | (dst&63)<<17) into bucket regions.
// 4 B entries appended densely -> far less write amplification than CSR scatter.
__global__ void bfill_kernel(const int* __restrict__ e0, const int* __restrict__ e1,
                             const int* __restrict__ e2,
                             int* __restrict__ bcursor, int* __restrict__ packed) {
    int e = blockIdx.x * blockDim.x + threadIdx.x;
    if (e >= N_EDGES) return;
    int r = blockIdx.y;
    const int* ei = (r == 0) ? e0 : (r == 1 ? e1 : e2);
    int src = ei[e], dst = ei[N_EDGES + e];
    int p = atomicAdd(&bcursor[r * NB + (dst >> 6)], 1);
    packed[(size_t)r * N_EDGES + p] = src | ((dst & 63) << 17);
}

// ---------------------------------------------------------------------------
// Bucket -> CSR: one block per bucket. LDS histogram of 64 node degrees,
// 64-wide scan for local rowstarts, LDS-cursor scatter writes adj densely.
// Emits per-node cnt + rowstart (dense stores, no global atomics).
__global__ __launch_bounds__(256) void csrify_kernel(
    const int* __restrict__ packed_all, const int* __restrict__ bstart_all,
    int* __restrict__ cnt, int* __restrict__ rowstart, int* __restrict__ adj_all) {
    int b = blockIdx.x, r = blockIdx.y;
    const int* packed = packed_all + (size_t)r * N_EDGES;
    int* adj = adj_all + (size_t)r * N_EDGES;
    const int* bstart = bstart_all + r * (NB + 1);
    __shared__ int deg[64], sbase[64], cur[64];
    int tid = threadIdx.x;
    if (tid < 64) { deg[tid] = 0; cur[tid] = 0; }
    __syncthreads();
    int estart = bstart[b], eend = bstart[b + 1];
    for (int e = estart + tid; e < eend; e += 256)
        atomicAdd(&deg[(packed[e] >> 17) & 63], 1);
    __syncthreads();
    if (tid < 64) {                       // wave 0 exactly
        int d = deg[tid];
        int incl = d;
#pragma unroll
        for (int off = 1; off < 64; off <<= 1) {
            int t = __shfl_up(incl, off);
            if (tid >= off) incl += t;
        }
        int base = estart + incl - d;     // exclusive
        sbase[tid] = base;
        int node = b * 64 + tid;
        if (node < N_NODES) {
            cnt[r * N_NODES + node] = d;
            rowstart[r * N_NODES + node] = base;
        }
    }
    __syncthreads();
    for (int e = estart + tid; e < eend; e += 256) {
        int v = packed[e];
        int d = (v >> 17) & 63;
        int pos = sbase[d] + atomicAdd(&cur[d], 1);
        adj[pos] = v & 0x1FFFF;
    }
}

// ---------------------------------------------------------------------------
// x (fp32) -> xb (bf16), 8 elems/thread.
__global__ void xcast_kernel(const float* __restrict__ x, unsigned short* __restrict__ xb) {
    int idx = blockIdx.x * 256 + threadIdx.x;
    const float4* p = (const float4*)x + (size_t)idx * 2;
    float4 a = p[0], b = p[1];
    ushort8v o;
    o[0] = f2b(a.x); o[1] = f2b(a.y); o[2] = f2b(a.z); o[3] = f2b(a.w);
    o[4] = f2b(b.x); o[5] = f2b(b.y); o[6] = f2b(b.z); o[7] = f2b(b.w);
    *(ushort8v*)(xb + (size_t)idx * 8) = o;
}

// ---------------------------------------------------------------------------
// Pre-swizzle weights into MFMA B-fragment order (coalesced lane*16B bursts).
__global__ void wprep_kernel(const float* __restrict__ Wl, const float* __restrict__ Wr,
                             const float* __restrict__ Wl_f, const float* __restrict__ Wr_f,
                             unsigned short* __restrict__ Wfrag, unsigned short* __restrict__ Wfrag2) {
    int idx = blockIdx.x * 256 + threadIdx.x;      // 448 blocks = 114688 threads
    int j = idx & 7, lane = (idx >> 3) & 63;
    int quad = lane >> 4, l16 = lane & 15;
    if (idx < 98304) {
        int t = (idx >> 9) & 1, s = (idx >> 10) & 7, w = (idx >> 13) & 3, r = idx >> 15;
        int k = s * 32 + quad * 8 + j;
        int n = w * 32 + t * 16 + l16;
        float v = (k < 128) ? Wl[((size_t)r * 128 + k) * 128 + n]
                            : Wr[((size_t)r * 128 + (k - 128)) * 128 + n];
        Wfrag[idx] = f2b(v);
    } else {
        int i2 = idx - 98304;
        if (i2 < 16384) {
            int t = (i2 >> 9) & 1, s = (i2 >> 10) & 3, w = (i2 >> 12) & 3;
            int k = s * 32 + quad * 8 + j;
            int n = w * 32 + t * 16 + l16;
            float v = (n < 64) ? Wl_f[(size_t)k * 64 + n] : Wr_f[(size_t)k * 64 + (n - 64)];
            Wfrag2[i2] = f2b(v);
        }
    }
}

// ---------------------------------------------------------------------------
// Gather-mean, 128 bf16 channels: one wave per node, 16 lanes per row
// (ushort8 = 16 B/lane), 4 rows/batch x2 unroll, shfl_xor reduce.
__global__ void gather128_kernel(const unsigned short* __restrict__ xb, const int* __restrict__ adj,
                                 const int* __restrict__ rowstart, const int* __restrict__ cnt,
                                 unsigned short* __restrict__ aggb) {
    int node = (blockIdx.x * blockDim.x + threadIdx.x) >> 6;
    int lane = threadIdx.x & 63;
    if (node >= N_NODES) return;
    int sub = lane >> 4, l16 = lane & 15;
    int start = rowstart[node];
    int deg = cnt[node];
    float acc[8];
#pragma unroll
    for (int i = 0; i < 8; i++) acc[i] = 0.f;
    int j = sub;
    for (; j + 4 < deg; j += 8) {
        int s0 = adj[start + j];
        int s1 = adj[start + j + 4];
        ushort8v v0 = *(const ushort8v*)(xb + (size_t)s0 * 128 + l16 * 8);
        ushort8v v1 = *(const ushort8v*)(xb + (size_t)s1 * 128 + l16 * 8);
#pragma unroll
        for (int i = 0; i < 8; i++) acc[i] += b2f(v0[i]) + b2f(v1[i]);
    }
    if (j < deg) {
        int s0 = adj[start + j];
        ushort8v v0 = *(const ushort8v*)(xb + (size_t)s0 * 128 + l16 * 8);
#pragma unroll
        for (int i = 0; i < 8; i++) acc[i] += b2f(v0[i]);
    }
#pragma unroll
    for (int i = 0; i < 8; i++) {
        acc[i] += __shfl_xor(acc[i], 16);
        acc[i] += __shfl_xor(acc[i], 32);
    }
    if (sub == 0) {
        float inv = 1.0f / fmaxf((float)deg, 1.0f);
        ushort8v o;
#pragma unroll
        for (int i = 0; i < 8; i++) o[i] = f2b(acc[i] * inv);
        *(ushort8v*)(aggb + (size_t)node * 128 + l16 * 8) = o;
    }
}

// ---------------------------------------------------------------------------
// Layer-1 for one relation: hb (+)= relu([agg|x](K=256) @ W + bl) / 3  (bf16 RMW)
__global__ __launch_bounds__(256, 4) void layer1_kernel(
    const unsigned short* __restrict__ aggb, const unsigned short* __restrict__ xb,
    const unsigned short* __restrict__ Wfrag, const float* __restrict__ bl,
    unsigned short* __restrict__ hb, int first) {
    __shared__ unsigned short s_a[64 * LDS_STRIDE];
    __shared__ unsigned short s_x[64 * LDS_STRIDE];
    int tid = threadIdx.x, wave = tid >> 6, lane = tid & 63;
    int quad = lane >> 4, l16 = lane & 15;
    int rowbase = blockIdx.x * 64;

#pragma unroll
    for (int it = 0; it < 4; it++) {
        int idx = tid + it * 256;
        int row = idx >> 4, c = idx & 15;
        int grow = rowbase + row;
        short8 xv = {0, 0, 0, 0, 0, 0, 0, 0};
        if (grow < N_NODES) xv = *(const short8*)(xb + (size_t)grow * 128 + c * 8);
        *(short8*)&s_x[row * LDS_STRIDE + c * 8] = xv;
        short8 av = *(const short8*)(aggb + (size_t)(rowbase + row) * 128 + c * 8);
        *(short8*)&s_a[row * LDS_STRIDE + c * 8] = av;
    }
    __syncthreads();

    f32x4 acc[4][2];
#pragma unroll
    for (int g = 0; g < 4; g++) { acc[g][0] = (f32x4){0.f,0.f,0.f,0.f}; acc[g][1] = (f32x4){0.f,0.f,0.f,0.f}; }

    const unsigned short* W = Wfrag + wave * 8192;
#pragma unroll
    for (int s = 0; s < 8; s++) {
        short8 bf0 = *(const short8*)(W + s * 1024 + lane * 8);
        short8 bf1 = *(const short8*)(W + s * 1024 + 512 + lane * 8);
        const unsigned short* src = (s < 4) ? s_a : s_x;
        int ko = (s & 3) * 32 + quad * 8;
#pragma unroll
        for (int g = 0; g < 4; g++) {
            short8 af = *(const short8*)&src[(g * 16 + l16) * LDS_STRIDE + ko];
            acc[g][0] = __builtin_amdgcn_mfma_f32_16x16x32_bf16(af, bf0, acc[g][0], 0, 0, 0);
            acc[g][1] = __builtin_amdgcn_mfma_f32_16x16x32_bf16(af, bf1, acc[g][1], 0, 0, 0);
        }
    }

    float b0 = bl[wave * 32 + l16];
    float b1 = bl[wave * 32 + 16 + l16];
#pragma unroll
    for (int g = 0; g < 4; g++)
#pragma unroll
        for (int t = 0; t < 2; t++) {
            float bb = t ? b1 : b0;
            int col = wave * 32 + t * 16 + l16;
#pragma unroll
            for (int q = 0; q < 4; q++) {
                int row = rowbase + g * 16 + quad * 4 + q;
                if (row < N_NODES) {
                    float v = fmaxf(acc[g][t][q] + bb, 0.f) * (1.0f / 3.0f);
                    size_t o = (size_t)row * 128 + col;
                    if (!first) v += b2f(hb[o]);
                    hb[o] = f2b(v);
                }
            }
        }
}

// ---------------------------------------------------------------------------
// Layer-2: [hWl|hWr] = h @ Wf2 (K=128); hWl -> bf16 buffer, out = hWr + bl_f.
__global__ __launch_bounds__(256, 4) void layer2_kernel(
    const unsigned short* __restrict__ hb, const unsigned short* __restrict__ Wfrag2,
    const float* __restrict__ bl_f, unsigned short* __restrict__ hWlb,
    float* __restrict__ out) {
    __shared__ unsigned short s_h[64 * LDS_STRIDE];
    int tid = threadIdx.x, wave = tid >> 6, lane = tid & 63;
    int quad = lane >> 4, l16 = lane & 15;
    int rowbase = blockIdx.x * 64;

#pragma unroll
    for (int it = 0; it < 4; it++) {
        int idx = tid + it * 256;
        int row = idx >> 4, c = idx & 15;
        int grow = rowbase + row;
        short8 hv = {0, 0, 0, 0, 0, 0, 0, 0};
        if (grow < N_NODES) hv = *(const short8*)(hb + (size_t)grow * 128 + c * 8);
        *(short8*)&s_h[row * LDS_STRIDE + c * 8] = hv;
    }
    __syncthreads();

    f32x4 acc[4][2];
#pragma unroll
    for (int g = 0; g < 4; g++) { acc[g][0] = (f32x4){0.f,0.f,0.f,0.f}; acc[g][1] = (f32x4){0.f,0.f,0.f,0.f}; }

    const unsigned short* W = Wfrag2 + wave * 4096;
#pragma unroll
    for (int s = 0; s < 4; s++) {
        short8 bf0 = *(const short8*)(W + s * 1024 + lane * 8);
        short8 bf1 = *(const short8*)(W + s * 1024 + 512 + lane * 8);
        int ko = s * 32 + quad * 8;
#pragma unroll
        for (int g = 0; g < 4; g++) {
            short8 af = *(const short8*)&s_h[(g * 16 + l16) * LDS_STRIDE + ko];
            acc[g][0] = __builtin_amdgcn_mfma_f32_16x16x32_bf16(af, bf0, acc[g][0], 0, 0, 0);
            acc[g][1] = __builtin_amdgcn_mfma_f32_16x16x32_bf16(af, bf1, acc[g][1], 0, 0, 0);
        }
    }

#pragma unroll
    for (int g = 0; g < 4; g++)
#pragma unroll
        for (int t = 0; t < 2; t++) {
            int col = wave * 32 + t * 16 + l16;
#pragma unroll
            for (int q = 0; q < 4; q++) {
                int row = rowbase + g * 16 + quad * 4 + q;
                if (row < N_NODES) {
                    if (col < 64) hWlb[(size_t)row * 64 + col] = f2b(acc[g][t][q]);
                    else out[(size_t)row * 64 + (col - 64)] = acc[g][t][q] + bl_f[col - 64];
                }
            }
        }
}

// ---------------------------------------------------------------------------
// Gather-mean of hWl (bf16, 64 ch = 128 B rows) + add into out.
__global__ void gather64_kernel(const unsigned short* __restrict__ hWlb, const int* __restrict__ adj,
                                const int* __restrict__ rowstart, const int* __restrict__ cnt,
                                float* __restrict__ out) {
    int node = (blockIdx.x * blockDim.x + threadIdx.x) >> 6;
    int lane = threadIdx.x & 63;
    if (node >= N_NODES) return;
    int sub = lane >> 3, l8 = lane & 7;
    int start = rowstart[node];
    int deg = cnt[node];
    float acc[8];
#pragma unroll
    for (int i = 0; i < 8; i++) acc[i] = 0.f;
    int j = sub;
    for (; j + 8 < deg; j += 16) {
        int s0 = adj[start + j];
        int s1 = adj[start + j + 8];
        ushort8v v0 = *(const ushort8v*)(hWlb + (size_t)s0 * 64 + l8 * 8);
        ushort8v v1 = *(const ushort8v*)(hWlb + (size_t)s1 * 64 + l8 * 8);
#pragma unroll
        for (int i = 0; i < 8; i++) acc[i] += b2f(v0[i]) + b2f(v1[i]);
    }
    if (j < deg) {
        int s0 = adj[start + j];
        ushort8v v0 = *(const ushort8v*)(hWlb + (size_t)s0 * 64 + l8 * 8);
#pragma unroll
        for (int i = 0; i < 8; i++) acc[i] += b2f(v0[i]);
    }
#pragma unroll
    for (int i = 0; i < 8; i++) {
        acc[i] += __shfl_xor(acc[i], 8);
        acc[i] += __shfl_xor(acc[i], 16);
        acc[i] += __shfl_xor(acc[i], 32);
    }
    if (sub == 0) {
        float inv = 1.0f / fmaxf((float)deg, 1.0f);
        float4* po = (float4*)(out + (size_t)node * 64 + l8 * 8);
        float4 a = po[0], b = po[1];
        a.x += acc[0] * inv; a.y += acc[1] * inv; a.z += acc[2] * inv; a.w += acc[3] * inv;
        b.x += acc[4] * inv; b.y += acc[5] * inv; b.z += acc[6] * inv; b.w += acc[7] * inv;
        po[0] = a; po[1] = b;
    }
}

// ---------------------------------------------------------------------------
extern "C" void kernel_launch(void* const* d_in, const int* in_sizes, int n_in,
                              void* d_out, int out_size, void* d_ws, size_t ws_size,
                              hipStream_t stream) {
    const float* x    = (const float*)d_in[0];
    const float* Wl   = (const float*)d_in[1];
    const float* bl   = (const float*)d_in[2];
    const float* Wr   = (const float*)d_in[3];
    const float* Wl_f = (const float*)d_in[4];
    const float* bl_f = (const float*)d_in[5];
    const float* Wr_f = (const float*)d_in[6];
    const int* ei0 = (const int*)d_in[7];
    const int* ei1 = (const int*)d_in[8];
    const int* ei2 = (const int*)d_in[9];
    float* out = (float*)d_out;

    // workspace layout, total ~98.6 MB (hWlb aliases aggb — dead after layer1 r=2)
    char* ws = (char*)d_ws;
    int* bcnt              = (int*)(ws);                                   // 18.8 KB
    int* bcursor           = (int*)(ws + ((size_t)64  << 10));             // 18.8 KB
    int* bstart            = (int*)(ws + ((size_t)128 << 10));             // 18.8 KB
    unsigned short* Wfrag  = (unsigned short*)(ws + ((size_t)256 << 10));  // 192 KB
    unsigned short* Wfrag2 = (unsigned short*)(ws + ((size_t)448 << 10));  // 32 KB
    int* cnt               = (int*)(ws + ((size_t)1  << 20));              // 1.2 MB
    int* rowstart          = (int*)(ws + ((size_t)3  << 20));              // 1.2 MB
    int* packed            = (int*)(ws + ((size_t)5  << 20));              // 7.2 MB
    int* adj               = (int*)(ws + ((size_t)13 << 20));              // 7.2 MB
    unsigned short* xb     = (unsigned short*)(ws + ((size_t)21 << 20));   // 25.6 MB
    unsigned short* aggb   = (unsigned short*)(ws + ((size_t)47 << 20));   // 25.6 MB
    unsigned short* hWlb   = aggb;                                         // alias
    unsigned short* hb     = (unsigned short*)(ws + ((size_t)73 << 20));   // 25.6 MB

    hipMemsetAsync(bcnt, 0, 3 * NB * sizeof(int), stream);

    dim3 ge((N_EDGES + 255) / 256, 3);
    bhist_kernel<<<ge, 256, 0, stream>>>(ei0, ei1, ei2, bcnt);
    bscan_kernel<<<3, 1024, 0, stream>>>(bcnt, bstart, bcursor);
    bfill_kernel<<<ge, 256, 0, stream>>>(ei0, ei1, ei2, bcursor, packed);
    csrify_kernel<<<dim3(NB, 3), 256, 0, stream>>>(packed, bstart, cnt, rowstart, adj);
    wprep_kernel<<<448, 256, 0, stream>>>(Wl, Wr, Wl_f, Wr_f, Wfrag, Wfrag2);
    xcast_kernel<<<(N_NODES * 128 / 8) / 256, 256, 0, stream>>>(x, xb);

    const int GATHER_BLOCKS = (N_NODES + 3) / 4;   // one wave per node
    const int TILE_BLOCKS = (N_NODES + 63) / 64;   // 1563
    for (int r = 0; r < 3; r++) {
        gather128_kernel<<<GATHER_BLOCKS, 256, 0, stream>>>(
            xb, adj + (size_t)r * N_EDGES, rowstart + r * N_NODES, cnt + r * N_NODES, aggb);
        layer1_kernel<<<TILE_BLOCKS, 256, 0, stream>>>(
            aggb, xb, Wfrag + (size_t)r * 32768, bl + r * 128, hb, r == 0 ? 1 : 0);
    }

    layer2_kernel<<<TILE_BLOCKS, 256, 0, stream>>>(hb, Wfrag2, bl_f, hWlb, out);
    gather64_kernel<<<GATHER_BLOCKS, 256, 0, stream>>>(hWlb, adj, rowstart, cnt, out);
}